// Round 1
// baseline (745.258 us; speedup 1.0000x reference)
//
#include <hip/hip_runtime.h>

// Spiking self-attention block (spikformer SSA), MI355X fp32 implementation.
// T=4 B=32 C=384 H=W=14 (N=196), heads=8, d=48.
//
// Key exactness facts used here:
//  - LIF spikes are EXACTLY 0.0f/1.0f (soft + fl(hard-soft) rounds to hard).
//  - Therefore attention (q.kT, attn.v) is exact integer arithmetic in fp32,
//    order-independent; q.kT done via 48-bit popcount.
//  - Conv GEMM: single fp32 accumulator per output, ascending K, fused fmaf
//    (matches typical hipBLASLt accumulation). BN/LIF use __f*_rn to forbid
//    contraction (XLA elementwise code does mul-then-add, not fma).

#define T_ 4
#define B_ 32
#define C_ 384
#define N_ 196
#define NH_ 8
#define D_ 48
#define TB_ (T_ * B_)                 // 128
#define BCN4_ (B_ * C_ * (N_ / 4))    // 602112 float4 units per (g,t)
#define TBCN_ ((size_t)T_ * B_ * C_ * N_)  // 9,633,792 floats

// ---------------------------------------------------------------------------
// K1/K5: Y[g][tb][co][n] = sum_c Wg[co][c] * X[tb][c][n]
// grid: x = ntile(4)*cotile(6)=24, y = tb(128), z = g
// ---------------------------------------------------------------------------
__global__ __launch_bounds__(256) void gemm384(
    const float* __restrict__ X, const float* __restrict__ W0,
    const float* __restrict__ W1, const float* __restrict__ W2,
    float* __restrict__ P)
{
  const int g = blockIdx.z;
  const float* __restrict__ W = (g == 0) ? W0 : (g == 1) ? W1 : W2;
  const int tb = blockIdx.y;
  const int n0 = (blockIdx.x & 3) * 64;
  const int co0 = (blockIdx.x >> 2) * 64;
  __shared__ float As[16][64];  // [k][co']
  __shared__ float Bs[16][64];  // [k][n']
  const int tid = threadIdx.x;
  const int tx = tid & 15, ty = tid >> 4;
  float acc[4][4] = {};
  const float* Xb = X + (size_t)tb * C_ * N_;
  const int ar = tid >> 2, ac = (tid & 3) * 4;   // A-tile load coords
  const int bk = tid >> 4, bn = (tid & 15) * 4;  // B-tile load coords
  for (int c0 = 0; c0 < C_; c0 += 16) {
    const float4 a4 = *(const float4*)(W + (size_t)(co0 + ar) * C_ + c0 + ac);
    As[ac + 0][ar] = a4.x; As[ac + 1][ar] = a4.y;
    As[ac + 2][ar] = a4.z; As[ac + 3][ar] = a4.w;
    float4 b4 = make_float4(0.f, 0.f, 0.f, 0.f);
    if (n0 + bn < N_) b4 = *(const float4*)(Xb + (size_t)(c0 + bk) * N_ + n0 + bn);
    *(float4*)&Bs[bk][bn] = b4;
    __syncthreads();
#pragma unroll
    for (int kk = 0; kk < 16; ++kk) {
      const float4 av = *(const float4*)&As[kk][ty * 4];
      const float4 bv = *(const float4*)&Bs[kk][tx * 4];
      const float a[4] = {av.x, av.y, av.z, av.w};
      const float b[4] = {bv.x, bv.y, bv.z, bv.w};
#pragma unroll
      for (int i = 0; i < 4; ++i)
#pragma unroll
        for (int j = 0; j < 4; ++j)
          acc[i][j] = fmaf(a[i], b[j], acc[i][j]);
    }
    __syncthreads();
  }
  const int n = n0 + tx * 4;
  if (n < N_) {
#pragma unroll
    for (int i = 0; i < 4; ++i) {
      const float4 o = make_float4(acc[i][0], acc[i][1], acc[i][2], acc[i][3]);
      *(float4*)&P[((size_t)(g * TB_ + tb) * C_ + co0 + ty * 4 + i) * N_ + n] = o;
    }
  }
}

// ---------------------------------------------------------------------------
// K2/K4/K6: multi-step LIF over t (optionally with folded BN). In-place safe.
// One thread owns one float4 of (g,b,c,n) across all 4 timesteps.
// ---------------------------------------------------------------------------
__global__ __launch_bounds__(256) void lif4(
    const float* __restrict__ In, float* __restrict__ Out,
    const float* __restrict__ s0, const float* __restrict__ b0,
    const float* __restrict__ s1, const float* __restrict__ b1,
    const float* __restrict__ s2, const float* __restrict__ b2,
    float vth, int ng)
{
  const long u = (long)blockIdx.x * 256 + threadIdx.x;
  if (u >= (long)ng * BCN4_) return;
  const int g = (int)(u / BCN4_);
  const long r = u % BCN4_;
  const int c = (int)((r / (N_ / 4)) % C_);
  const float* sp = (g == 0) ? s0 : (g == 1) ? s1 : s2;
  const float* bp = (g == 0) ? b0 : (g == 1) ? b1 : b2;
  const bool has_bn = (sp != nullptr);
  const float sc = has_bn ? sp[c] : 1.0f;
  const float bi = has_bn ? bp[c] : 0.0f;
  const float4* In4 = (const float4*)In;
  float4* Out4 = (float4*)Out;
  float v[4] = {0.f, 0.f, 0.f, 0.f};
#pragma unroll
  for (int t = 0; t < T_; ++t) {
    const long idx = (long)(g * T_ + t) * BCN4_ + r;
    const float4 y4 = In4[idx];
    float y[4] = {y4.x, y4.y, y4.z, y4.w};
    float o[4];
#pragma unroll
    for (int e = 0; e < 4; ++e) {
      const float yb = has_bn ? __fadd_rn(__fmul_rn(y[e], sc), bi) : y[e];
      // v = v + (y - v)/2  (division by 2 exact; forbid fma contraction)
      v[e] = __fadd_rn(v[e], __fmul_rn(__fsub_rn(yb, v[e]), 0.5f));
      const bool fire = (v[e] >= vth);
      o[e] = fire ? 1.0f : 0.0f;
      v[e] = fire ? 0.0f : v[e];  // hard reset
    }
    Out4[idx] = make_float4(o[0], o[1], o[2], o[3]);
  }
}

// ---------------------------------------------------------------------------
// K3: fused spiking attention for one (t*b, head):
//   S[n][m] = popcount(qbits[n] & kbits[m]); O[n][dd] = 0.125 * sum_m S*V
// Exact integer arithmetic (spikes are binary, sums < 2^24).
// ---------------------------------------------------------------------------
__global__ __launch_bounds__(256) void attn196(
    const float* __restrict__ Q, const float* __restrict__ K,
    const float* __restrict__ V, float* __restrict__ O)
{
  const int h = blockIdx.x, tb = blockIdx.y;
  __shared__ unsigned long long qb[N_], kb[N_];
  __shared__ float vsh[N_][D_];
  const int tid = threadIdx.x;
  const size_t base = ((size_t)tb * C_ + h * D_) * N_;
  if (tid < N_) {
    unsigned long long qm = 0ull, km = 0ull;
    for (int dd = 0; dd < D_; ++dd) {
      if (Q[base + (size_t)dd * N_ + tid] > 0.5f) qm |= 1ull << dd;
      if (K[base + (size_t)dd * N_ + tid] > 0.5f) km |= 1ull << dd;
    }
    qb[tid] = qm; kb[tid] = km;
  }
  for (int u = tid; u < N_ * D_; u += 256) {
    const int dd = u / N_, m = u % N_;  // consecutive u -> consecutive m: coalesced
    vsh[m][dd] = V[base + (size_t)dd * N_ + m];
  }
  __syncthreads();
  if (tid < N_) {
    const unsigned long long qm = qb[tid];
    float out[D_];
#pragma unroll
    for (int i = 0; i < D_; ++i) out[i] = 0.f;
    for (int m = 0; m < N_; ++m) {
      const float s = (float)__popcll(qm & kb[m]);
      const float4* vp = (const float4*)&vsh[m][0];
#pragma unroll
      for (int i = 0; i < D_ / 4; ++i) {
        const float4 vv = vp[i];
        out[4 * i + 0] = fmaf(s, vv.x, out[4 * i + 0]);
        out[4 * i + 1] = fmaf(s, vv.y, out[4 * i + 1]);
        out[4 * i + 2] = fmaf(s, vv.z, out[4 * i + 2]);
        out[4 * i + 3] = fmaf(s, vv.w, out[4 * i + 3]);
      }
    }
    for (int dd = 0; dd < D_; ++dd)
      O[base + (size_t)dd * N_ + tid] = out[dd] * 0.125f;  // *0.125 exact
  }
}

// ---------------------------------------------------------------------------
extern "C" void kernel_launch(void* const* d_in, const int* in_sizes, int n_in,
                              void* d_out, int out_size, void* d_ws, size_t ws_size,
                              hipStream_t stream) {
  const float* x  = (const float*)d_in[0];
  const float* wq = (const float*)d_in[1];
  const float* sq = (const float*)d_in[2];
  const float* bq = (const float*)d_in[3];
  const float* wk = (const float*)d_in[4];
  const float* sk = (const float*)d_in[5];
  const float* bk = (const float*)d_in[6];
  const float* wv = (const float*)d_in[7];
  const float* sv = (const float*)d_in[8];
  const float* bv = (const float*)d_in[9];
  const float* wp = (const float*)d_in[10];
  const float* sp = (const float*)d_in[11];
  const float* bp = (const float*)d_in[12];
  float* out = (float*)d_out;

  // Workspace layout (floats): P[3*TBCN] qkv preact->spikes, O[TBCN] attn.
  // Final-conv preact P2 reuses the q-spike region (dead after attention).
  // Total: 4*TBCN*4B = 154.1 MB.
  float* P = (float*)d_ws;
  float* O = P + 3 * TBCN_;
  float* P2 = P;

  // 1) q,k,v conv preacts (BN folded into LIF kernel)
  gemm384<<<dim3(24, TB_, 3), 256, 0, stream>>>(x, wq, wk, wv, P);
  // 2) LIF th=1.0 with BN -> binary spikes (in place)
  lif4<<<dim3(3 * BCN4_ / 256), 256, 0, stream>>>(P, P, sq, bq, sk, bk, sv, bv, 1.0f, 3);
  // 3) attention per (t*b, head) -> O (scaled by 0.125)
  attn196<<<dim3(NH_, TB_), 256, 0, stream>>>(P, P + TBCN_, P + 2 * TBCN_, O);
  // 4) LIF th=0.5, no BN (in place)
  lif4<<<dim3(BCN4_ / 256), 256, 0, stream>>>(O, O, nullptr, nullptr, nullptr,
                                              nullptr, nullptr, nullptr, 0.5f, 1);
  // 5) final conv preact
  gemm384<<<dim3(24, TB_, 1), 256, 0, stream>>>(O, wp, wp, wp, P2);
  // 6) LIF th=1.0 with BN -> d_out
  lif4<<<dim3(BCN4_ / 256), 256, 0, stream>>>(P2, out, sp, bp, nullptr, nullptr,
                                              nullptr, nullptr, 1.0f, 1);
}

// Round 2
// 694.586 us; speedup vs baseline: 1.0730x; 1.0730x over previous
//
#include <hip/hip_runtime.h>

// Spiking self-attention block (spikformer SSA), MI355X fp32 implementation.
// T=4 B=32 C=384 H=W=14 (N=196), heads=8, d=48.
//
// Exactness: LIF spikes are EXACTLY 0/1; attention is exact integer math.
// Conv GEMM: single fp32 accumulator per output, ascending K, fmaf per step
// (matched XLA bit-for-bit in round 1, absmax=0.0). The 8x8-tile rewrite
// keeps the identical per-output FMA chain.

#define T_ 4
#define B_ 32
#define C_ 384
#define N_ 196
#define NH_ 8
#define D_ 48
#define TB_ (T_ * B_)                 // 128
#define CN_ ((size_t)C_ * N_)         // 75264
#define BCN4_ (B_ * C_ * (N_ / 4))    // 602112 float4 units per (g,t)
#define TBCN_ ((size_t)T_ * B_ * C_ * N_)  // 9,633,792 floats

// ---------------------------------------------------------------------------
// GEMM: Y[g][tb][co][n] = sum_c Wg[co][c] * X[tb][c][n]
// Columns flattened: j = tb*196 + n, 25088 = 196 tiles of 128 (exact).
// Block: 128co x 128col, 256 threads, 8x8 per thread. 1 B LDS per MAC.
// grid: x = col-tile (196), y = co-tile (3), z = g
// ---------------------------------------------------------------------------
__global__ __launch_bounds__(256, 4) void gemm_f32(
    const float* __restrict__ X, const float* __restrict__ W0,
    const float* __restrict__ W1, const float* __restrict__ W2,
    float* __restrict__ P)
{
  const int g = blockIdx.z;
  const float* __restrict__ W = (g == 0) ? W0 : (g == 1) ? W1 : W2;
  const int co0 = blockIdx.y * 128;
  const int j0 = blockIdx.x * 128;
  __shared__ float As[16][128];  // [k][co']
  __shared__ float Bs[16][128];  // [k][col']
  const int tid = threadIdx.x;
  const int tx = tid & 15, ty = tid >> 4;

  // B staging: this thread loads cols bcol..bcol+3 for k = bk and bk+8
  const int bcol = (tid & 31) * 4;
  const int bk = tid >> 5;
  size_t boff[4];
#pragma unroll
  for (int i = 0; i < 4; ++i) {
    const int j = j0 + bcol + i;
    const int tb = j / N_;
    boff[i] = (size_t)tb * CN_ + (j - tb * N_);
  }
  // A staging: this thread loads W[co0+arow][c0+ac8 .. +7]
  const int arow = tid >> 1;
  const int ac8 = (tid & 1) * 8;

  float acc[8][8] = {};
  for (int c0 = 0; c0 < C_; c0 += 16) {
    const float* wp_ = W + (size_t)(co0 + arow) * C_ + c0 + ac8;
    const float4 a0 = *(const float4*)wp_;
    const float4 a1 = *(const float4*)(wp_ + 4);
    As[ac8 + 0][arow] = a0.x; As[ac8 + 1][arow] = a0.y;
    As[ac8 + 2][arow] = a0.z; As[ac8 + 3][arow] = a0.w;
    As[ac8 + 4][arow] = a1.x; As[ac8 + 5][arow] = a1.y;
    As[ac8 + 6][arow] = a1.z; As[ac8 + 7][arow] = a1.w;
#pragma unroll
    for (int kh = 0; kh < 2; ++kh) {
      const int k = bk + kh * 8;
      const float* xp = X + (size_t)(c0 + k) * N_;
#pragma unroll
      for (int i = 0; i < 4; ++i) Bs[k][bcol + i] = xp[boff[i]];
    }
    __syncthreads();
#pragma unroll
    for (int k = 0; k < 16; ++k) {
      float a[8], b[8];
      *(float4*)&a[0] = *(const float4*)&As[k][ty * 8];
      *(float4*)&a[4] = *(const float4*)&As[k][ty * 8 + 4];
      *(float4*)&b[0] = *(const float4*)&Bs[k][tx * 8];
      *(float4*)&b[4] = *(const float4*)&Bs[k][tx * 8 + 4];
#pragma unroll
      for (int i = 0; i < 8; ++i)
#pragma unroll
        for (int j = 0; j < 8; ++j)
          acc[i][j] = fmaf(a[i], b[j], acc[i][j]);
    }
    __syncthreads();
  }
  // epilogue: scalar stores (cols may cross a tb boundary)
  int tbv[8], nv[8];
#pragma unroll
  for (int j = 0; j < 8; ++j) {
    const int jj = j0 + tx * 8 + j;
    const int tb = jj / N_;
    tbv[j] = tb; nv[j] = jj - tb * N_;
  }
#pragma unroll
  for (int i = 0; i < 8; ++i) {
    const int co = co0 + ty * 8 + i;
#pragma unroll
    for (int j = 0; j < 8; ++j)
      P[(size_t)(g * TB_ + tbv[j]) * CN_ + (size_t)co * N_ + nv[j]] = acc[i][j];
  }
}

// ---------------------------------------------------------------------------
// Multi-step LIF over t (optionally with folded BN). In-place safe.
// ---------------------------------------------------------------------------
__global__ __launch_bounds__(256) void lif4(
    const float* __restrict__ In, float* __restrict__ Out,
    const float* __restrict__ s0, const float* __restrict__ b0,
    const float* __restrict__ s1, const float* __restrict__ b1,
    const float* __restrict__ s2, const float* __restrict__ b2,
    float vth, int ng)
{
  const long u = (long)blockIdx.x * 256 + threadIdx.x;
  if (u >= (long)ng * BCN4_) return;
  const int g = (int)(u / BCN4_);
  const long r = u % BCN4_;
  const int c = (int)((r / (N_ / 4)) % C_);
  const float* sp = (g == 0) ? s0 : (g == 1) ? s1 : s2;
  const float* bp = (g == 0) ? b0 : (g == 1) ? b1 : b2;
  const bool has_bn = (sp != nullptr);
  const float sc = has_bn ? sp[c] : 1.0f;
  const float bi = has_bn ? bp[c] : 0.0f;
  const float4* In4 = (const float4*)In;
  float4* Out4 = (float4*)Out;
  float v[4] = {0.f, 0.f, 0.f, 0.f};
#pragma unroll
  for (int t = 0; t < T_; ++t) {
    const long idx = (long)(g * T_ + t) * BCN4_ + r;
    const float4 y4 = In4[idx];
    float y[4] = {y4.x, y4.y, y4.z, y4.w};
    float o[4];
#pragma unroll
    for (int e = 0; e < 4; ++e) {
      const float yb = has_bn ? __fadd_rn(__fmul_rn(y[e], sc), bi) : y[e];
      v[e] = __fadd_rn(v[e], __fmul_rn(__fsub_rn(yb, v[e]), 0.5f));
      const bool fire = (v[e] >= vth);
      o[e] = fire ? 1.0f : 0.0f;
      v[e] = fire ? 0.0f : v[e];
    }
    Out4[idx] = make_float4(o[0], o[1], o[2], o[3]);
  }
}

// ---------------------------------------------------------------------------
// Fused spiking attention for one (t*b, head) via 48-bit popcount. Exact.
// ---------------------------------------------------------------------------
__global__ __launch_bounds__(256) void attn196(
    const float* __restrict__ Q, const float* __restrict__ K,
    const float* __restrict__ V, float* __restrict__ O)
{
  const int h = blockIdx.x, tb = blockIdx.y;
  __shared__ unsigned long long qb[N_], kb[N_];
  __shared__ float vsh[N_][D_];
  const int tid = threadIdx.x;
  const size_t base = ((size_t)tb * C_ + h * D_) * N_;
  if (tid < N_) {
    unsigned long long qm = 0ull, km = 0ull;
    for (int dd = 0; dd < D_; ++dd) {
      if (Q[base + (size_t)dd * N_ + tid] > 0.5f) qm |= 1ull << dd;
      if (K[base + (size_t)dd * N_ + tid] > 0.5f) km |= 1ull << dd;
    }
    qb[tid] = qm; kb[tid] = km;
  }
  for (int u = tid; u < N_ * D_; u += 256) {
    const int dd = u / N_, m = u % N_;
    vsh[m][dd] = V[base + (size_t)dd * N_ + m];
  }
  __syncthreads();
  if (tid < N_) {
    const unsigned long long qm = qb[tid];
    float out[D_];
#pragma unroll
    for (int i = 0; i < D_; ++i) out[i] = 0.f;
    for (int m = 0; m < N_; ++m) {
      const float s = (float)__popcll(qm & kb[m]);
      const float4* vp = (const float4*)&vsh[m][0];
#pragma unroll
      for (int i = 0; i < D_ / 4; ++i) {
        const float4 vv = vp[i];
        out[4 * i + 0] = fmaf(s, vv.x, out[4 * i + 0]);
        out[4 * i + 1] = fmaf(s, vv.y, out[4 * i + 1]);
        out[4 * i + 2] = fmaf(s, vv.z, out[4 * i + 2]);
        out[4 * i + 3] = fmaf(s, vv.w, out[4 * i + 3]);
      }
    }
    for (int dd = 0; dd < D_; ++dd)
      O[base + (size_t)dd * N_ + tid] = out[dd] * 0.125f;
  }
}

// ---------------------------------------------------------------------------
extern "C" void kernel_launch(void* const* d_in, const int* in_sizes, int n_in,
                              void* d_out, int out_size, void* d_ws, size_t ws_size,
                              hipStream_t stream) {
  const float* x  = (const float*)d_in[0];
  const float* wq = (const float*)d_in[1];
  const float* sq = (const float*)d_in[2];
  const float* bq = (const float*)d_in[3];
  const float* wk = (const float*)d_in[4];
  const float* sk = (const float*)d_in[5];
  const float* bk = (const float*)d_in[6];
  const float* wv = (const float*)d_in[7];
  const float* sv = (const float*)d_in[8];
  const float* bv = (const float*)d_in[9];
  const float* wp = (const float*)d_in[10];
  const float* sp = (const float*)d_in[11];
  const float* bp = (const float*)d_in[12];
  float* out = (float*)d_out;

  float* P = (float*)d_ws;          // 3*TBCN qkv preact -> spikes
  float* O = P + 3 * TBCN_;         // TBCN attn out
  float* P2 = P;                    // final conv preact reuses q region

  gemm_f32<<<dim3(196, 3, 3), 256, 0, stream>>>(x, wq, wk, wv, P);
  lif4<<<dim3(3 * BCN4_ / 256), 256, 0, stream>>>(P, P, sq, bq, sk, bk, sv, bv, 1.0f, 3);
  attn196<<<dim3(NH_, TB_), 256, 0, stream>>>(P, P + TBCN_, P + 2 * TBCN_, O);
  lif4<<<dim3(BCN4_ / 256), 256, 0, stream>>>(O, O, nullptr, nullptr, nullptr,
                                              nullptr, nullptr, nullptr, 0.5f, 1);
  gemm_f32<<<dim3(196, 3, 1), 256, 0, stream>>>(O, wp, wp, wp, P2);
  lif4<<<dim3(BCN4_ / 256), 256, 0, stream>>>(P2, out, sp, bp, nullptr, nullptr,
                                              nullptr, nullptr, 1.0f, 1);
}

// Round 3
// 587.893 us; speedup vs baseline: 1.2677x; 1.1815x over previous
//
#include <hip/hip_runtime.h>

// Spiking self-attention block (spikformer SSA), MI355X fp32 implementation.
// T=4 B=32 C=384 H=W=14 (N=196), heads=8, d=48.
//
// Exactness: LIF spikes are EXACTLY 0/1; attention is exact integer math.
// Conv GEMM: single fp32 accumulator per output, ascending K, fmaf per step
// (matched XLA bit-for-bit in rounds 1-2, absmax=0.0).
//
// R3: __launch_bounds__(256,2) (R2's (256,4) forced VGPR=64 -> scratch spill,
// +180MB WRITE_SIZE). float4 B-staging + float4 epilogue (legal because
// 196 % 4 == 0: a 4-col group never straddles a tb boundary). Thread tile
// split into stride-64 quads so LDS b-reads are 16B apart (2-way bank
// aliasing = free, vs 4-way before).

#define T_ 4
#define B_ 32
#define C_ 384
#define N_ 196
#define NH_ 8
#define D_ 48
#define TB_ (T_ * B_)                 // 128
#define CN_ ((size_t)C_ * N_)         // 75264
#define BCN4_ (B_ * C_ * (N_ / 4))    // 602112 float4 units per (g,t)
#define TBCN_ ((size_t)T_ * B_ * C_ * N_)  // 9,633,792 floats

// ---------------------------------------------------------------------------
// GEMM: Y[g][tb][co][n] = sum_c Wg[co][c] * X[tb][c][n]
// Columns flattened: j = tb*196 + n, 25088 = 196 tiles of 128 (exact).
// Block: 128co x 128col, 256 threads, 8x8 per thread (two stride-64 quads).
// grid: x = col-tile (196), y = co-tile (3), z = g
// ---------------------------------------------------------------------------
__global__ __launch_bounds__(256, 2) void gemm_f32(
    const float* __restrict__ X, const float* __restrict__ W0,
    const float* __restrict__ W1, const float* __restrict__ W2,
    float* __restrict__ P)
{
  const int g = blockIdx.z;
  const float* __restrict__ W = (g == 0) ? W0 : (g == 1) ? W1 : W2;
  const int co0 = blockIdx.y * 128;
  const int j0 = blockIdx.x * 128;
  __shared__ float As[16][128];  // [k][co']
  __shared__ float Bs[16][128];  // [k][col']
  const int tid = threadIdx.x;
  const int tx = tid & 15, ty = tid >> 4;

  // B staging: thread loads float4 at col quad bcol, rows k=bk and bk+8.
  // 4-col group never straddles tb (196%4==0, bcol%4==0) -> single float4.
  const int bcol = (tid & 31) * 4;
  const int bk = tid >> 5;
  const int bj = j0 + bcol;
  const int btb = bj / N_;
  const float* xb = X + (size_t)btb * CN_ + (bj - btb * N_);
  // A staging: thread loads W[co0+arow][c0+ac8 .. +7], scatter to As[k][co].
  const int arow = tid >> 1;
  const int ac8 = (tid & 1) * 8;

  float acc[8][8] = {};
  for (int c0 = 0; c0 < C_; c0 += 16) {
    const float* wrow = W + (size_t)(co0 + arow) * C_ + c0 + ac8;
    const float4 a0 = *(const float4*)wrow;
    const float4 a1 = *(const float4*)(wrow + 4);
    As[ac8 + 0][arow] = a0.x; As[ac8 + 1][arow] = a0.y;
    As[ac8 + 2][arow] = a0.z; As[ac8 + 3][arow] = a0.w;
    As[ac8 + 4][arow] = a1.x; As[ac8 + 5][arow] = a1.y;
    As[ac8 + 6][arow] = a1.z; As[ac8 + 7][arow] = a1.w;
    *(float4*)&Bs[bk][bcol]     = *(const float4*)(xb + (size_t)(c0 + bk) * N_);
    *(float4*)&Bs[bk + 8][bcol] = *(const float4*)(xb + (size_t)(c0 + bk + 8) * N_);
    __syncthreads();
#pragma unroll
    for (int k = 0; k < 16; ++k) {
      float a[8], b[8];
      *(float4*)&a[0] = *(const float4*)&As[k][ty * 4];
      *(float4*)&a[4] = *(const float4*)&As[k][64 + ty * 4];
      *(float4*)&b[0] = *(const float4*)&Bs[k][tx * 4];
      *(float4*)&b[4] = *(const float4*)&Bs[k][64 + tx * 4];
#pragma unroll
      for (int i = 0; i < 8; ++i)
#pragma unroll
        for (int j = 0; j < 8; ++j)
          acc[i][j] = fmaf(a[i], b[j], acc[i][j]);
    }
    __syncthreads();
  }
  // Epilogue: all float4 stores (4-col quads never straddle tb).
#pragma unroll
  for (int cg = 0; cg < 2; ++cg) {
    const int jj = j0 + cg * 64 + tx * 4;
    const int tb = jj / N_;
    float* pb = P + (size_t)(g * TB_ + tb) * CN_ + (jj - tb * N_);
#pragma unroll
    for (int rg = 0; rg < 2; ++rg) {
#pragma unroll
      for (int i = 0; i < 4; ++i) {
        const int r = rg * 4 + i;
        const int co = co0 + rg * 64 + ty * 4 + i;
        *(float4*)&pb[(size_t)co * N_] = make_float4(
            acc[r][cg * 4 + 0], acc[r][cg * 4 + 1],
            acc[r][cg * 4 + 2], acc[r][cg * 4 + 3]);
      }
    }
  }
}

// ---------------------------------------------------------------------------
// Multi-step LIF over t (optionally with folded BN). In-place safe.
// ---------------------------------------------------------------------------
__global__ __launch_bounds__(256) void lif4(
    const float* __restrict__ In, float* __restrict__ Out,
    const float* __restrict__ s0, const float* __restrict__ b0,
    const float* __restrict__ s1, const float* __restrict__ b1,
    const float* __restrict__ s2, const float* __restrict__ b2,
    float vth, int ng)
{
  const long u = (long)blockIdx.x * 256 + threadIdx.x;
  if (u >= (long)ng * BCN4_) return;
  const int g = (int)(u / BCN4_);
  const long r = u % BCN4_;
  const int c = (int)((r / (N_ / 4)) % C_);
  const float* sp = (g == 0) ? s0 : (g == 1) ? s1 : s2;
  const float* bp = (g == 0) ? b0 : (g == 1) ? b1 : b2;
  const bool has_bn = (sp != nullptr);
  const float sc = has_bn ? sp[c] : 1.0f;
  const float bi = has_bn ? bp[c] : 0.0f;
  const float4* In4 = (const float4*)In;
  float4* Out4 = (float4*)Out;
  float v[4] = {0.f, 0.f, 0.f, 0.f};
#pragma unroll
  for (int t = 0; t < T_; ++t) {
    const long idx = (long)(g * T_ + t) * BCN4_ + r;
    const float4 y4 = In4[idx];
    float y[4] = {y4.x, y4.y, y4.z, y4.w};
    float o[4];
#pragma unroll
    for (int e = 0; e < 4; ++e) {
      const float yb = has_bn ? __fadd_rn(__fmul_rn(y[e], sc), bi) : y[e];
      v[e] = __fadd_rn(v[e], __fmul_rn(__fsub_rn(yb, v[e]), 0.5f));
      const bool fire = (v[e] >= vth);
      o[e] = fire ? 1.0f : 0.0f;
      v[e] = fire ? 0.0f : v[e];
    }
    Out4[idx] = make_float4(o[0], o[1], o[2], o[3]);
  }
}

// ---------------------------------------------------------------------------
// Fused spiking attention for one (t*b, head) via 48-bit popcount. Exact.
// ---------------------------------------------------------------------------
__global__ __launch_bounds__(256) void attn196(
    const float* __restrict__ Q, const float* __restrict__ K,
    const float* __restrict__ V, float* __restrict__ O)
{
  const int h = blockIdx.x, tb = blockIdx.y;
  __shared__ unsigned long long qb[N_], kb[N_];
  __shared__ float vsh[N_][D_];
  const int tid = threadIdx.x;
  const size_t base = ((size_t)tb * C_ + h * D_) * N_;
  if (tid < N_) {
    unsigned long long qm = 0ull, km = 0ull;
    for (int dd = 0; dd < D_; ++dd) {
      if (Q[base + (size_t)dd * N_ + tid] > 0.5f) qm |= 1ull << dd;
      if (K[base + (size_t)dd * N_ + tid] > 0.5f) km |= 1ull << dd;
    }
    qb[tid] = qm; kb[tid] = km;
  }
  for (int u = tid; u < N_ * D_; u += 256) {
    const int dd = u / N_, m = u % N_;
    vsh[m][dd] = V[base + (size_t)dd * N_ + m];
  }
  __syncthreads();
  if (tid < N_) {
    const unsigned long long qm = qb[tid];
    float out[D_];
#pragma unroll
    for (int i = 0; i < D_; ++i) out[i] = 0.f;
    for (int m = 0; m < N_; ++m) {
      const float s = (float)__popcll(qm & kb[m]);
      const float4* vp = (const float4*)&vsh[m][0];
#pragma unroll
      for (int i = 0; i < D_ / 4; ++i) {
        const float4 vv = vp[i];
        out[4 * i + 0] = fmaf(s, vv.x, out[4 * i + 0]);
        out[4 * i + 1] = fmaf(s, vv.y, out[4 * i + 1]);
        out[4 * i + 2] = fmaf(s, vv.z, out[4 * i + 2]);
        out[4 * i + 3] = fmaf(s, vv.w, out[4 * i + 3]);
      }
    }
    for (int dd = 0; dd < D_; ++dd)
      O[base + (size_t)dd * N_ + tid] = out[dd] * 0.125f;
  }
}

// ---------------------------------------------------------------------------
extern "C" void kernel_launch(void* const* d_in, const int* in_sizes, int n_in,
                              void* d_out, int out_size, void* d_ws, size_t ws_size,
                              hipStream_t stream) {
  const float* x  = (const float*)d_in[0];
  const float* wq = (const float*)d_in[1];
  const float* sq = (const float*)d_in[2];
  const float* bq = (const float*)d_in[3];
  const float* wk = (const float*)d_in[4];
  const float* sk = (const float*)d_in[5];
  const float* bk = (const float*)d_in[6];
  const float* wv = (const float*)d_in[7];
  const float* sv = (const float*)d_in[8];
  const float* bv = (const float*)d_in[9];
  const float* wp = (const float*)d_in[10];
  const float* sp = (const float*)d_in[11];
  const float* bp = (const float*)d_in[12];
  float* out = (float*)d_out;

  float* P = (float*)d_ws;          // 3*TBCN qkv preact -> spikes
  float* O = P + 3 * TBCN_;         // TBCN attn out
  float* P2 = P;                    // final conv preact reuses q region

  gemm_f32<<<dim3(196, 3, 3), 256, 0, stream>>>(x, wq, wk, wv, P);
  lif4<<<dim3(3 * BCN4_ / 256), 256, 0, stream>>>(P, P, sq, bq, sk, bk, sv, bv, 1.0f, 3);
  attn196<<<dim3(NH_, TB_), 256, 0, stream>>>(P, P + TBCN_, P + 2 * TBCN_, O);
  lif4<<<dim3(BCN4_ / 256), 256, 0, stream>>>(O, O, nullptr, nullptr, nullptr,
                                              nullptr, nullptr, nullptr, 0.5f, 1);
  gemm_f32<<<dim3(196, 3, 1), 256, 0, stream>>>(O, wp, wp, wp, P2);
  lif4<<<dim3(BCN4_ / 256), 256, 0, stream>>>(P2, out, sp, bp, nullptr, nullptr,
                                              nullptr, nullptr, 1.0f, 1);
}

// Round 4
// 540.080 us; speedup vs baseline: 1.3799x; 1.0885x over previous
//
#include <hip/hip_runtime.h>

// Spiking self-attention block (spikformer SSA), MI355X fp32 implementation.
// T=4 B=32 C=384 H=W=14 (N=196), heads=8, d=48.
//
// Exactness: LIF spikes are EXACTLY 0/1; attention is exact integer math
// (order-independent). Conv GEMM: single fp32 accumulator per output,
// ascending K, fmaf per step (matched XLA bit-for-bit rounds 1-3).
//
// R4: fused LIF+attention kernel per (b,h). Algebraic trick: since q,k,v
// are binary, out[n][d] = sum_j q[n][j] * G[j][d] with
// G[j][d] = popcount_m(kbit[j] & vbit[d]) — contracts m=196 via popcount
// (4x less work than the PV FMA loop), all exact integer arithmetic.
// Eliminates the standalone qkv-LIF pass, attention spike re-read, and
// attn-LIF pass (~220 us -> ~50 us predicted).

#define T_ 4
#define B_ 32
#define C_ 384
#define N_ 196
#define NH_ 8
#define D_ 48
#define TB_ (T_ * B_)                 // 128
#define CN_ ((size_t)C_ * N_)         // 75264
#define BCN4_ (B_ * C_ * (N_ / 4))    // 602112 float4 units per (g,t)
#define TBCN_ ((size_t)T_ * B_ * C_ * N_)  // 9,633,792 floats
typedef unsigned long long u64;

// ---------------------------------------------------------------------------
// GEMM: Y[g][tb][co][n] = sum_c Wg[co][c] * X[tb][c][n]  (unchanged from R3)
// ---------------------------------------------------------------------------
__global__ __launch_bounds__(256, 2) void gemm_f32(
    const float* __restrict__ X, const float* __restrict__ W0,
    const float* __restrict__ W1, const float* __restrict__ W2,
    float* __restrict__ P)
{
  const int g = blockIdx.z;
  const float* __restrict__ W = (g == 0) ? W0 : (g == 1) ? W1 : W2;
  const int co0 = blockIdx.y * 128;
  const int j0 = blockIdx.x * 128;
  __shared__ float As[16][128];
  __shared__ float Bs[16][128];
  const int tid = threadIdx.x;
  const int tx = tid & 15, ty = tid >> 4;

  const int bcol = (tid & 31) * 4;
  const int bk = tid >> 5;
  const int bj = j0 + bcol;
  const int btb = bj / N_;
  const float* xb = X + (size_t)btb * CN_ + (bj - btb * N_);
  const int arow = tid >> 1;
  const int ac8 = (tid & 1) * 8;

  float acc[8][8] = {};
  for (int c0 = 0; c0 < C_; c0 += 16) {
    const float* wrow = W + (size_t)(co0 + arow) * C_ + c0 + ac8;
    const float4 a0 = *(const float4*)wrow;
    const float4 a1 = *(const float4*)(wrow + 4);
    As[ac8 + 0][arow] = a0.x; As[ac8 + 1][arow] = a0.y;
    As[ac8 + 2][arow] = a0.z; As[ac8 + 3][arow] = a0.w;
    As[ac8 + 4][arow] = a1.x; As[ac8 + 5][arow] = a1.y;
    As[ac8 + 6][arow] = a1.z; As[ac8 + 7][arow] = a1.w;
    *(float4*)&Bs[bk][bcol]     = *(const float4*)(xb + (size_t)(c0 + bk) * N_);
    *(float4*)&Bs[bk + 8][bcol] = *(const float4*)(xb + (size_t)(c0 + bk + 8) * N_);
    __syncthreads();
#pragma unroll
    for (int k = 0; k < 16; ++k) {
      float a[8], b[8];
      *(float4*)&a[0] = *(const float4*)&As[k][ty * 4];
      *(float4*)&a[4] = *(const float4*)&As[k][64 + ty * 4];
      *(float4*)&b[0] = *(const float4*)&Bs[k][tx * 4];
      *(float4*)&b[4] = *(const float4*)&Bs[k][64 + tx * 4];
#pragma unroll
      for (int i = 0; i < 8; ++i)
#pragma unroll
        for (int j = 0; j < 8; ++j)
          acc[i][j] = fmaf(a[i], b[j], acc[i][j]);
    }
    __syncthreads();
  }
#pragma unroll
  for (int cg = 0; cg < 2; ++cg) {
    const int jj = j0 + cg * 64 + tx * 4;
    const int tb = jj / N_;
    float* pb = P + (size_t)(g * TB_ + tb) * CN_ + (jj - tb * N_);
#pragma unroll
    for (int rg = 0; rg < 2; ++rg) {
#pragma unroll
      for (int i = 0; i < 4; ++i) {
        const int r = rg * 4 + i;
        const int co = co0 + rg * 64 + ty * 4 + i;
        *(float4*)&pb[(size_t)co * N_] = make_float4(
            acc[r][cg * 4 + 0], acc[r][cg * 4 + 1],
            acc[r][cg * 4 + 2], acc[r][cg * 4 + 3]);
      }
    }
  }
}

// ---------------------------------------------------------------------------
// Multi-step LIF over t with folded BN (used only for the final conv now).
// ---------------------------------------------------------------------------
__global__ __launch_bounds__(256) void lif4(
    const float* __restrict__ In, float* __restrict__ Out,
    const float* __restrict__ s0, const float* __restrict__ b0, float vth)
{
  const long u = (long)blockIdx.x * 256 + threadIdx.x;
  if (u >= BCN4_) return;
  const long r = u;
  const int c = (int)((r / (N_ / 4)) % C_);
  const bool has_bn = (s0 != nullptr);
  const float sc = has_bn ? s0[c] : 1.0f;
  const float bi = has_bn ? b0[c] : 0.0f;
  const float4* In4 = (const float4*)In;
  float4* Out4 = (float4*)Out;
  float v[4] = {0.f, 0.f, 0.f, 0.f};
#pragma unroll
  for (int t = 0; t < T_; ++t) {
    const long idx = (long)t * BCN4_ + r;
    const float4 y4 = In4[idx];
    float y[4] = {y4.x, y4.y, y4.z, y4.w};
    float o[4];
#pragma unroll
    for (int e = 0; e < 4; ++e) {
      const float yb = has_bn ? __fadd_rn(__fmul_rn(y[e], sc), bi) : y[e];
      v[e] = __fadd_rn(v[e], __fmul_rn(__fsub_rn(yb, v[e]), 0.5f));
      const bool fire = (v[e] >= vth);
      o[e] = fire ? 1.0f : 0.0f;
      v[e] = fire ? 0.0f : v[e];
    }
    Out4[idx] = make_float4(o[0], o[1], o[2], o[3]);
  }
}

// ---------------------------------------------------------------------------
// Fused qkv-LIF + attention + attn-LIF. One block per (h, b), 1024 threads.
// Phase A: LIF on preacts -> bitmasks msk[g][t][j][word] via __ballot.
// Phase B per t: G[j][d] = popcount_m(k & v); out[n][d] = sum_j q * G;
//               attn-LIF (membrane in regs across t); write binary spikes.
// ---------------------------------------------------------------------------
__global__ __launch_bounds__(1024) void fused_attn(
    const float* __restrict__ P, float* __restrict__ O,
    const float* __restrict__ sq, const float* __restrict__ bq,
    const float* __restrict__ sk, const float* __restrict__ bk,
    const float* __restrict__ sv, const float* __restrict__ bv)
{
  const int h = blockIdx.x;   // 8
  const int b = blockIdx.y;   // 32
  __shared__ u64 msk[3][T_][D_][4];   // [g][t][j][mword]  18.4 KB
  __shared__ float G[D_][52];         // 9.98 KB
  const int tid = threadIdx.x;
  const int wave = tid >> 6, lane = tid & 63;

  // ---- Phase A: conv-LIF -> spike bitmasks (wave-task = (g, j, mword)) ----
  for (int task = wave; task < 3 * D_ * 4; task += 16) {
    const int g = task / (D_ * 4);
    const int rem = task - g * (D_ * 4);
    const int j = rem >> 2, w = rem & 3;
    const int m = w * 64 + lane;
    const bool act = (m < N_);
    const int mc = act ? m : (N_ - 1);
    const int c = h * D_ + j;
    const float sc = (g == 0 ? sq : g == 1 ? sk : sv)[c];
    const float bi = (g == 0 ? bq : g == 1 ? bk : bv)[c];
    const float* base = P + (size_t)g * TB_ * CN_ + (size_t)b * CN_
                          + (size_t)c * N_ + mc;
    float v = 0.f;
#pragma unroll
    for (int t = 0; t < T_; ++t) {
      const float y = base[(size_t)t * B_ * CN_];
      const float yb = __fadd_rn(__fmul_rn(y, sc), bi);
      v = __fadd_rn(v, __fmul_rn(__fsub_rn(yb, v), 0.5f));
      const bool fire = (v >= 1.0f);
      if (fire) v = 0.f;
      const u64 bl = __ballot(fire && act);
      if (lane == 0) msk[g][t][j][w] = bl;
    }
  }
  __syncthreads();

  // ---- Phase B: per-t attention + attn-LIF ----
  const int u = tid;
  const bool ow = (u < 4 * N_);           // 784 worker threads
  const int dq = ow ? (u / N_) : 0;       // d-quarter 0..3
  const int n = ow ? (u - dq * N_) : 0;   // 0..195
  const int d0 = dq * 12;
  const int nw = n >> 6, nb = n & 63;
  float vmem[12];
#pragma unroll
  for (int i = 0; i < 12; ++i) vmem[i] = 0.f;

  for (int t = 0; t < T_; ++t) {
    // G[j][d] = popcount over m of (kbit[j] & vbit[d])
    for (int e = tid; e < D_ * D_; e += 1024) {
      const int j = e / D_, d = e - j * D_;
      const u64* kj = msk[1][t][j];
      const u64* vd = msk[2][t][d];
      const int s = __popcll(kj[0] & vd[0]) + __popcll(kj[1] & vd[1]) +
                    __popcll(kj[2] & vd[2]) + __popcll(kj[3] & vd[3]);
      G[j][d] = (float)s;
    }
    __syncthreads();
    if (ow) {
      float out[12];
#pragma unroll
      for (int i = 0; i < 12; ++i) out[i] = 0.f;
#pragma unroll 4
      for (int j = 0; j < D_; ++j) {
        const u64 qw = msk[0][t][j][nw];
        const float qf = (float)((qw >> nb) & 1ull);
        const float* Gj = &G[j][d0];
        const float4 g0 = *(const float4*)&Gj[0];
        const float4 g1 = *(const float4*)&Gj[4];
        const float4 g2 = *(const float4*)&Gj[8];
        out[0] = fmaf(qf, g0.x, out[0]);  out[1] = fmaf(qf, g0.y, out[1]);
        out[2] = fmaf(qf, g0.z, out[2]);  out[3] = fmaf(qf, g0.w, out[3]);
        out[4] = fmaf(qf, g1.x, out[4]);  out[5] = fmaf(qf, g1.y, out[5]);
        out[6] = fmaf(qf, g1.z, out[6]);  out[7] = fmaf(qf, g1.w, out[7]);
        out[8] = fmaf(qf, g2.x, out[8]);  out[9] = fmaf(qf, g2.y, out[9]);
        out[10] = fmaf(qf, g2.z, out[10]); out[11] = fmaf(qf, g2.w, out[11]);
      }
      // attn-LIF (th=0.5): all operands exact dyadic -> order-independent
      float* ob = O + ((size_t)(t * B_ + b) * C_ + h * D_ + d0) * N_ + n;
#pragma unroll
      for (int i = 0; i < 12; ++i) {
        const float y = out[i] * 0.125f;  // exact
        vmem[i] = __fadd_rn(vmem[i], __fmul_rn(__fsub_rn(y, vmem[i]), 0.5f));
        const bool fire = (vmem[i] >= 0.5f);
        ob[(size_t)i * N_] = fire ? 1.0f : 0.0f;
        if (fire) vmem[i] = 0.f;
      }
    }
    __syncthreads();  // protect G (and msk reads) before next-t overwrite
  }
}

// ---------------------------------------------------------------------------
extern "C" void kernel_launch(void* const* d_in, const int* in_sizes, int n_in,
                              void* d_out, int out_size, void* d_ws, size_t ws_size,
                              hipStream_t stream) {
  const float* x  = (const float*)d_in[0];
  const float* wq = (const float*)d_in[1];
  const float* sq = (const float*)d_in[2];
  const float* bq = (const float*)d_in[3];
  const float* wk = (const float*)d_in[4];
  const float* sk = (const float*)d_in[5];
  const float* bk = (const float*)d_in[6];
  const float* wv = (const float*)d_in[7];
  const float* sv = (const float*)d_in[8];
  const float* bv = (const float*)d_in[9];
  const float* wp = (const float*)d_in[10];
  const float* sp = (const float*)d_in[11];
  const float* bp = (const float*)d_in[12];
  float* out = (float*)d_out;

  float* P = (float*)d_ws;          // 3*TBCN qkv preacts
  float* O = P + 3 * TBCN_;         // TBCN attn spikes
  float* P2 = P;                    // final conv preact reuses q region

  gemm_f32<<<dim3(196, 3, 3), 256, 0, stream>>>(x, wq, wk, wv, P);
  fused_attn<<<dim3(NH_, B_), 1024, 0, stream>>>(P, O, sq, bq, sk, bk, sv, bv);
  gemm_f32<<<dim3(196, 3, 1), 256, 0, stream>>>(O, wp, wp, wp, P2);
  lif4<<<dim3((BCN4_ + 255) / 256), 256, 0, stream>>>(P2, out, sp, bp, 1.0f);
}

// Round 5
// 536.376 us; speedup vs baseline: 1.3894x; 1.0069x over previous
//
#include <hip/hip_runtime.h>

// Spiking self-attention block (spikformer SSA), MI355X fp32 implementation.
// T=4 B=32 C=384 H=W=14 (N=196), heads=8, d=48.
//
// Exactness: LIF spikes are EXACTLY 0/1; attention is exact integer math
// (order-independent). Conv GEMM: single fp32 accumulator per output,
// ascending K, fmaf per step (matched XLA bit-for-bit rounds 1-4).
//
// R5: fused_attn restructure. Phase A issues all 4 t-loads before the LIF
// recurrence (was a 4-deep dependent chain -> ~4x latency). Phase B stores
// G = K^T.V as 8 bit-planes over j (G<=196<256) built via ballot, q-masks
// transposed to 48-bit rows; apply = sum_p 2^p popcount(qr & Gp[p][d]).
// All Gp/qT built once -> no barriers inside the t loop.

#define T_ 4
#define B_ 32
#define C_ 384
#define N_ 196
#define NH_ 8
#define D_ 48
#define TB_ (T_ * B_)                 // 128
#define CN_ ((size_t)C_ * N_)         // 75264
#define BCN4_ (B_ * C_ * (N_ / 4))    // 602112 float4 units per (g,t)
#define TBCN_ ((size_t)T_ * B_ * C_ * N_)  // 9,633,792 floats
typedef unsigned long long u64;

// ---------------------------------------------------------------------------
// GEMM: Y[g][tb][co][n] = sum_c Wg[co][c] * X[tb][c][n]  (unchanged from R3)
// ---------------------------------------------------------------------------
__global__ __launch_bounds__(256, 2) void gemm_f32(
    const float* __restrict__ X, const float* __restrict__ W0,
    const float* __restrict__ W1, const float* __restrict__ W2,
    float* __restrict__ P)
{
  const int g = blockIdx.z;
  const float* __restrict__ W = (g == 0) ? W0 : (g == 1) ? W1 : W2;
  const int co0 = blockIdx.y * 128;
  const int j0 = blockIdx.x * 128;
  __shared__ float As[16][128];
  __shared__ float Bs[16][128];
  const int tid = threadIdx.x;
  const int tx = tid & 15, ty = tid >> 4;

  const int bcol = (tid & 31) * 4;
  const int bk = tid >> 5;
  const int bj = j0 + bcol;
  const int btb = bj / N_;
  const float* xb = X + (size_t)btb * CN_ + (bj - btb * N_);
  const int arow = tid >> 1;
  const int ac8 = (tid & 1) * 8;

  float acc[8][8] = {};
  for (int c0 = 0; c0 < C_; c0 += 16) {
    const float* wrow = W + (size_t)(co0 + arow) * C_ + c0 + ac8;
    const float4 a0 = *(const float4*)wrow;
    const float4 a1 = *(const float4*)(wrow + 4);
    As[ac8 + 0][arow] = a0.x; As[ac8 + 1][arow] = a0.y;
    As[ac8 + 2][arow] = a0.z; As[ac8 + 3][arow] = a0.w;
    As[ac8 + 4][arow] = a1.x; As[ac8 + 5][arow] = a1.y;
    As[ac8 + 6][arow] = a1.z; As[ac8 + 7][arow] = a1.w;
    *(float4*)&Bs[bk][bcol]     = *(const float4*)(xb + (size_t)(c0 + bk) * N_);
    *(float4*)&Bs[bk + 8][bcol] = *(const float4*)(xb + (size_t)(c0 + bk + 8) * N_);
    __syncthreads();
#pragma unroll
    for (int k = 0; k < 16; ++k) {
      float a[8], b[8];
      *(float4*)&a[0] = *(const float4*)&As[k][ty * 4];
      *(float4*)&a[4] = *(const float4*)&As[k][64 + ty * 4];
      *(float4*)&b[0] = *(const float4*)&Bs[k][tx * 4];
      *(float4*)&b[4] = *(const float4*)&Bs[k][64 + tx * 4];
#pragma unroll
      for (int i = 0; i < 8; ++i)
#pragma unroll
        for (int j = 0; j < 8; ++j)
          acc[i][j] = fmaf(a[i], b[j], acc[i][j]);
    }
    __syncthreads();
  }
#pragma unroll
  for (int cg = 0; cg < 2; ++cg) {
    const int jj = j0 + cg * 64 + tx * 4;
    const int tb = jj / N_;
    float* pb = P + (size_t)(g * TB_ + tb) * CN_ + (jj - tb * N_);
#pragma unroll
    for (int rg = 0; rg < 2; ++rg) {
#pragma unroll
      for (int i = 0; i < 4; ++i) {
        const int r = rg * 4 + i;
        const int co = co0 + rg * 64 + ty * 4 + i;
        *(float4*)&pb[(size_t)co * N_] = make_float4(
            acc[r][cg * 4 + 0], acc[r][cg * 4 + 1],
            acc[r][cg * 4 + 2], acc[r][cg * 4 + 3]);
      }
    }
  }
}

// ---------------------------------------------------------------------------
// Multi-step LIF over t with folded BN (final conv only).
// ---------------------------------------------------------------------------
__global__ __launch_bounds__(256) void lif4(
    const float* __restrict__ In, float* __restrict__ Out,
    const float* __restrict__ s0, const float* __restrict__ b0, float vth)
{
  const long u = (long)blockIdx.x * 256 + threadIdx.x;
  if (u >= BCN4_) return;
  const long r = u;
  const int c = (int)((r / (N_ / 4)) % C_);
  const bool has_bn = (s0 != nullptr);
  const float sc = has_bn ? s0[c] : 1.0f;
  const float bi = has_bn ? b0[c] : 0.0f;
  const float4* In4 = (const float4*)In;
  float4* Out4 = (float4*)Out;
  float v[4] = {0.f, 0.f, 0.f, 0.f};
#pragma unroll
  for (int t = 0; t < T_; ++t) {
    const long idx = (long)t * BCN4_ + r;
    const float4 y4 = In4[idx];
    float y[4] = {y4.x, y4.y, y4.z, y4.w};
    float o[4];
#pragma unroll
    for (int e = 0; e < 4; ++e) {
      const float yb = has_bn ? __fadd_rn(__fmul_rn(y[e], sc), bi) : y[e];
      v[e] = __fadd_rn(v[e], __fmul_rn(__fsub_rn(yb, v[e]), 0.5f));
      const bool fire = (v[e] >= vth);
      o[e] = fire ? 1.0f : 0.0f;
      v[e] = fire ? 0.0f : v[e];
    }
    Out4[idx] = make_float4(o[0], o[1], o[2], o[3]);
  }
}

// ---------------------------------------------------------------------------
// Fused qkv-LIF + attention + attn-LIF. One block per (h, b), 1024 threads.
//  A: LIF -> bitmasks msk[g][t][j][w] (ballot, lanes=m). 4 loads prefetched.
//  A2: qT[t][n] = q bits over j (transpose); Gp[t][p][d] = plane p of
//      G[j][d] = popcount_m(k_j & v_d), built via ballot with lanes=j.
//  B: per t (no barriers): out[n][d] = sum_p 2^p popcount(qT & Gp[p][d]);
//     attn-LIF (membrane in regs); write binary spikes.
// ---------------------------------------------------------------------------
__global__ __launch_bounds__(1024) void fused_attn(
    const float* __restrict__ P, float* __restrict__ O,
    const float* __restrict__ sq, const float* __restrict__ bq,
    const float* __restrict__ sk, const float* __restrict__ bk,
    const float* __restrict__ sv, const float* __restrict__ bv)
{
  const int h = blockIdx.x;   // 8
  const int b = blockIdx.y;   // 32
  __shared__ u64 msk[3][T_][D_][4];   // 18432 B
  __shared__ u64 qT[T_][208];         // 6656 B   (n-indexed, padded)
  __shared__ u64 Gp[T_][8][D_];       // 12288 B
  const int tid = threadIdx.x;
  const int wave = tid >> 6, lane = tid & 63;

  // ---- Phase A: conv-LIF -> spike bitmasks (wave-task = (g, j, mword)) ----
  for (int task = wave; task < 3 * D_ * 4; task += 16) {
    const int g = task / (D_ * 4);
    const int rem = task - g * (D_ * 4);
    const int j = rem >> 2, w = rem & 3;
    const int m = w * 64 + lane;
    const bool act = (m < N_);
    const int mc = act ? m : (N_ - 1);
    const int c = h * D_ + j;
    const float sc = (g == 0 ? sq : g == 1 ? sk : sv)[c];
    const float bi = (g == 0 ? bq : g == 1 ? bk : bv)[c];
    const float* base = P + (size_t)g * TB_ * CN_ + (size_t)b * CN_
                          + (size_t)c * N_ + mc;
    float y[T_];
#pragma unroll
    for (int t = 0; t < T_; ++t) y[t] = base[(size_t)t * B_ * CN_];  // indep loads
    float v = 0.f;
#pragma unroll
    for (int t = 0; t < T_; ++t) {
      const float yb = __fadd_rn(__fmul_rn(y[t], sc), bi);
      v = __fadd_rn(v, __fmul_rn(__fsub_rn(yb, v), 0.5f));
      const bool fire = (v >= 1.0f);
      if (fire) v = 0.f;
      const u64 bl = __ballot(fire && act);
      if (lane == 0) msk[g][t][j][w] = bl;
    }
  }
  __syncthreads();

  // ---- Phase A2a: transpose q masks -> qT[t][n] (bits over j) ----
  {
    const int t = wave >> 2, w = wave & 3;   // 16 waves = 16 tasks
    const int n = w * 64 + lane;
    u64 qr = 0ull;
#pragma unroll 8
    for (int j = 0; j < D_; ++j)
      qr |= ((msk[0][t][j][w] >> lane) & 1ull) << j;
    if (n < N_) qT[t][n] = qr;
  }
  // ---- Phase A2b: G bit-planes via ballot (wave-task = (t,d), lanes=j) ----
  for (int task = wave; task < T_ * D_; task += 16) {
    const int t = task / D_, d = task - (task / D_) * D_;
    const bool ja = (lane < D_);
    const int j = ja ? lane : (D_ - 1);
    const u64* kj = msk[1][t][j];
    const u64* vd = msk[2][t][d];
    const int gi = __popcll(kj[0] & vd[0]) + __popcll(kj[1] & vd[1]) +
                   __popcll(kj[2] & vd[2]) + __popcll(kj[3] & vd[3]);
#pragma unroll
    for (int p = 0; p < 8; ++p) {
      const u64 bl = __ballot(ja && ((gi >> p) & 1));
      if (lane == 0) Gp[t][p][d] = bl;
    }
  }
  __syncthreads();

  // ---- Phase B: apply + attn-LIF, no barriers across t ----
  const int u = tid;
  if (u < 4 * N_) {
    const int dq = u / N_;
    const int n = u - dq * N_;
    const int d0 = dq * 12;
    float vmem[12];
#pragma unroll
    for (int i = 0; i < 12; ++i) vmem[i] = 0.f;
    for (int t = 0; t < T_; ++t) {
      const u64 qr = qT[t][n];
      float* ob = O + ((size_t)(t * B_ + b) * C_ + h * D_ + d0) * N_ + n;
#pragma unroll
      for (int i = 0; i < 12; ++i) {
        int acc = 0;
#pragma unroll
        for (int p = 0; p < 8; ++p)
          acc += __popcll(qr & Gp[t][p][d0 + i]) << p;
        const float y = __int2float_rn(acc) * 0.125f;  // exact
        vmem[i] = __fadd_rn(vmem[i], __fmul_rn(__fsub_rn(y, vmem[i]), 0.5f));
        const bool fire = (vmem[i] >= 0.5f);
        ob[(size_t)i * N_] = fire ? 1.0f : 0.0f;
        if (fire) vmem[i] = 0.f;
      }
    }
  }
}

// ---------------------------------------------------------------------------
extern "C" void kernel_launch(void* const* d_in, const int* in_sizes, int n_in,
                              void* d_out, int out_size, void* d_ws, size_t ws_size,
                              hipStream_t stream) {
  const float* x  = (const float*)d_in[0];
  const float* wq = (const float*)d_in[1];
  const float* sq = (const float*)d_in[2];
  const float* bq = (const float*)d_in[3];
  const float* wk = (const float*)d_in[4];
  const float* sk = (const float*)d_in[5];
  const float* bk = (const float*)d_in[6];
  const float* wv = (const float*)d_in[7];
  const float* sv = (const float*)d_in[8];
  const float* bv = (const float*)d_in[9];
  const float* wp = (const float*)d_in[10];
  const float* sp = (const float*)d_in[11];
  const float* bp = (const float*)d_in[12];
  float* out = (float*)d_out;

  float* P = (float*)d_ws;          // 3*TBCN qkv preacts
  float* O = P + 3 * TBCN_;         // TBCN attn spikes
  float* P2 = P;                    // final conv preact reuses q region

  gemm_f32<<<dim3(196, 3, 3), 256, 0, stream>>>(x, wq, wk, wv, P);
  fused_attn<<<dim3(NH_, B_), 1024, 0, stream>>>(P, O, sq, bq, sk, bk, sv, bv);
  gemm_f32<<<dim3(196, 3, 1), 256, 0, stream>>>(O, wp, wp, wp, P2);
  lif4<<<dim3((BCN4_ + 255) / 256), 256, 0, stream>>>(P2, out, sp, bp, 1.0f);
}